// Round 11
// baseline (123.623 us; speedup 1.0000x reference)
//
#include <hip/hip_runtime.h>
#include <hip/hip_bf16.h>
#include <stdint.h>

// Problem constants
#define B_   16
#define T_   5
#define C_   512
#define HW_  256          // H*W
#define NF_  10
#define KIN_ 1280         // T*H*W
#define GOUT_ 2560        // NF*H*W

typedef __attribute__((ext_vector_type(8))) short s16x8;
typedef __attribute__((ext_vector_type(4))) float f32x4;
typedef unsigned short u16;

__device__ __forceinline__ u16 f2bf(float x) {
    unsigned int u = __float_as_uint(x);
    return (u16)((u + 0x7FFFu + ((u >> 16) & 1u)) >> 16);
}

// ---------------------------------------------------------------------------
// Kernel 0 (merged init): blocks 0..4: wbar[k] = mean_f conv1_w[f,k] (+bbar)
//                         blocks 5..1604: G3 weight fp32->bf16 cast
// ---------------------------------------------------------------------------
#define CASTW_N8  (GOUT_ * KIN_ / 8) // 409600
#define CASTW_BLKS (CASTW_N8 / 256)  // 1600

__global__ __launch_bounds__(256) void k_init(const float* __restrict__ conv1_w,
                        const float* __restrict__ conv1_b,
                        float* __restrict__ wbar, float* __restrict__ bbar,
                        const float* __restrict__ g3w,
                        u16* __restrict__ wsA) {
    if (blockIdx.x < 5) {
        int k = blockIdx.x * 256 + threadIdx.x;   // 5*256 = 1280 exactly
        float s = 0.f;
        #pragma unroll
        for (int f = 0; f < NF_; ++f) s += conv1_w[f * KIN_ + k];
        wbar[k] = s * (1.0f / NF_);
        if (blockIdx.x == 0 && threadIdx.x == 0) {
            float sb = 0.f;
            #pragma unroll
            for (int f = 0; f < NF_; ++f) sb += conv1_b[f];
            *bbar = sb * (1.0f / NF_);
        }
        return;
    }
    int i = (blockIdx.x - 5) * 256 + threadIdx.x;
    if (i < CASTW_N8) {
        const float4* s = reinterpret_cast<const float4*>(g3w) + (size_t)i * 2;
        float4 v0 = s[0], v1 = s[1];
        union { u16 h[8]; int4 v; } u;
        u.h[0] = f2bf(v0.x); u.h[1] = f2bf(v0.y); u.h[2] = f2bf(v0.z); u.h[3] = f2bf(v0.w);
        u.h[4] = f2bf(v1.x); u.h[5] = f2bf(v1.y); u.h[6] = f2bf(v1.z); u.h[7] = f2bf(v1.w);
        reinterpret_cast<int4*>(wsA)[i] = u.v;
    }
}

// fallback-path wbar-only kernel
__global__ void k_wbar(const float* __restrict__ conv1_w,
                       const float* __restrict__ conv1_b,
                       float* __restrict__ wbar, float* __restrict__ bbar) {
    int k = blockIdx.x * blockDim.x + threadIdx.x;
    if (k < KIN_) {
        float s = 0.f;
        #pragma unroll
        for (int f = 0; f < NF_; ++f) s += conv1_w[f * KIN_ + k];
        wbar[k] = s * (1.0f / NF_);
    }
    if (blockIdx.x == 0 && threadIdx.x == 0) {
        float s = 0.f;
        #pragma unroll
        for (int f = 0; f < NF_; ++f) s += conv1_b[f];
        *bbar = s * (1.0f / NF_);
    }
}

// ---------------------------------------------------------------------------
// Kernel 1: pooled[b,c] + input->bf16 cast (single pass; 160 threads x 8)
// ---------------------------------------------------------------------------
#define FUSE_BLKS (B_ * C_)          // 8192

__global__ __launch_bounds__(256) void k_prep(const float* __restrict__ in,
                         const float* __restrict__ wbar,
                         const float* __restrict__ bbar,
                         float* __restrict__ pooled,
                         u16* __restrict__ X) {
    int bc = blockIdx.x;            // 0 .. B*C-1
    int b = bc >> 9;
    int c = bc & 511;
    int tid = threadIdx.x;

    float s = 0.f;
    if (tid < 160) {
        int t   = tid >> 5;          // 0..4
        int hw0 = (tid & 31) * 8;    // 0..248
        size_t off = ((size_t)(b * T_ + t) * C_ + c) * HW_ + hw0;
        const float4* ip = reinterpret_cast<const float4*>(in + off);
        float4 v0 = ip[0], v1 = ip[1];
        const float4* wp = reinterpret_cast<const float4*>(wbar + t * HW_ + hw0);
        float4 w0 = wp[0], w1 = wp[1];
        s = v0.x * w0.x + v0.y * w0.y + v0.z * w0.z + v0.w * w0.w
          + v1.x * w1.x + v1.y * w1.y + v1.z * w1.z + v1.w * w1.w;
        union { u16 h[8]; int4 q; } u;
        u.h[0] = f2bf(v0.x); u.h[1] = f2bf(v0.y); u.h[2] = f2bf(v0.z); u.h[3] = f2bf(v0.w);
        u.h[4] = f2bf(v1.x); u.h[5] = f2bf(v1.y); u.h[6] = f2bf(v1.z); u.h[7] = f2bf(v1.w);
        reinterpret_cast<int4*>(X + off)[0] = u.q;
    }

    #pragma unroll
    for (int off = 32; off > 0; off >>= 1) s += __shfl_down(s, off, 64);
    __shared__ float red[4];
    int wid = tid >> 6, lane = tid & 63;
    if (lane == 0) red[wid] = s;
    __syncthreads();
    if (tid == 0) {
        float tot = red[0] + red[1] + red[2] + red[3];
        pooled[bc] = tot + *bbar;
    }
}

// non-fused fallback (small-ws path)
__global__ __launch_bounds__(256) void k_pooled(const float* __restrict__ in,
                         const float* __restrict__ wbar,
                         const float* __restrict__ bbar,
                         float* __restrict__ pooled) {
    int bc = blockIdx.x;
    int b = bc >> 9;
    int c = bc & 511;
    int hw = threadIdx.x;
    const float* base = in + ((size_t)(b * T_) * C_ + c) * HW_;
    float s = 0.f;
    #pragma unroll
    for (int t = 0; t < T_; ++t)
        s = fmaf(wbar[t * HW_ + hw], base[(size_t)t * C_ * HW_ + hw], s);
    #pragma unroll
    for (int off = 32; off > 0; off >>= 1) s += __shfl_down(s, off, 64);
    __shared__ float red[4];
    int wid = threadIdx.x >> 6, lane = threadIdx.x & 63;
    if (lane == 0) red[wid] = s;
    __syncthreads();
    if (threadIdx.x == 0) {
        float tot = red[0] + red[1] + red[2] + red[3];
        pooled[bc] = tot + *bbar;
    }
}

// ---------------------------------------------------------------------------
// Kernel 2 (merged k_pre + k_act): one block per b (16 blocks x 512 thr).
//   waves compute pre[b,c] coalesced (wave w owns rows w*64..w*64+63; lane
//   reads w[c][lane*8..+7], butterfly-reduce), stash in LDS, then block
//   softmax + 3-activation combine -> scale[b,c].
// ---------------------------------------------------------------------------
__global__ __launch_bounds__(512) void k_prescale(const float* __restrict__ pooled,
                       const float* __restrict__ ffnn1_w,
                       const float* __restrict__ ffnn1_b,
                       const float* __restrict__ actw,
                       float* __restrict__ scale) {
    int b = blockIdx.x;
    int tid = threadIdx.x;
    int wid = tid >> 6, lane = tid & 63;
    __shared__ float spre[C_];
    __shared__ float redm[8], reds[8];

    const float4* pp = reinterpret_cast<const float4*>(pooled + b * C_ + lane * 8);
    float4 pa = pp[0], pb = pp[1];

    #pragma unroll 4
    for (int rr = 0; rr < 64; ++rr) {
        int c = wid * 64 + rr;
        const float4* wr = reinterpret_cast<const float4*>(ffnn1_w + (size_t)c * C_ + lane * 8);
        float4 wa = wr[0], wb2 = wr[1];
        float d = pa.x * wa.x + pa.y * wa.y + pa.z * wa.z + pa.w * wa.w
                + pb.x * wb2.x + pb.y * wb2.y + pb.z * wb2.z + pb.w * wb2.w;
        #pragma unroll
        for (int off = 32; off > 0; off >>= 1) d += __shfl_xor(d, off, 64);
        if (lane == 0) spre[c] = d + ffnn1_b[c];
    }
    __syncthreads();

    float p0 = spre[tid];
    float mx = p0;
    #pragma unroll
    for (int off = 32; off > 0; off >>= 1) mx = fmaxf(mx, __shfl_xor(mx, off, 64));
    if (lane == 0) redm[wid] = mx;
    __syncthreads();
    float m8 = redm[0];
    #pragma unroll
    for (int i = 1; i < 8; ++i) m8 = fmaxf(m8, redm[i]);
    float e0 = __expf(p0 - m8);
    float sm = e0;
    #pragma unroll
    for (int off = 32; off > 0; off >>= 1) sm += __shfl_xor(sm, off, 64);
    if (lane == 0) reds[wid] = sm;
    __syncthreads();
    float ssum = reds[0];
    #pragma unroll
    for (int i = 1; i < 8; ++i) ssum += reds[i];

    float aw0 = actw[0], aw1 = actw[1], aw2 = actw[2];
    scale[b * C_ + tid] = aw0 * fmaxf(p0, 0.f)
                        + aw1 * (1.f / (1.f + __expf(-p0)))
                        + aw2 * (e0 / ssum);
}

// ---------------------------------------------------------------------------
// Fallback-path scale kernel (original, from pooled)
// ---------------------------------------------------------------------------
__global__ __launch_bounds__(512) void k_scale(const float* __restrict__ pooled,
                        const float* __restrict__ ffnn1_w,
                        const float* __restrict__ ffnn1_b,
                        const float* __restrict__ actw,
                        float* __restrict__ scale) {
    int b = blockIdx.x;
    int c = threadIdx.x;
    __shared__ float sp[C_];
    __shared__ float red[8];

    sp[c] = pooled[b * C_ + c];
    __syncthreads();

    float acc = ffnn1_b[c];
    const float* wr = ffnn1_w + (size_t)c * C_;
    #pragma unroll 8
    for (int j = 0; j < C_; ++j) acc = fmaf(wr[j], sp[j], acc);

    int wid = c >> 6, lane = c & 63;
    float m = acc;
    #pragma unroll
    for (int off = 32; off > 0; off >>= 1) m = fmaxf(m, __shfl_down(m, off, 64));
    if (lane == 0) red[wid] = m;
    __syncthreads();
    if (c == 0) {
        float mm = red[0];
        #pragma unroll
        for (int i = 1; i < 8; ++i) mm = fmaxf(mm, red[i]);
        red[0] = mm;
    }
    __syncthreads();
    m = red[0];
    __syncthreads();

    float e = __expf(acc - m);
    float s = e;
    #pragma unroll
    for (int off = 32; off > 0; off >>= 1) s += __shfl_down(s, off, 64);
    if (lane == 0) red[wid] = s;
    __syncthreads();
    if (c == 0) {
        float ss = 0.f;
        #pragma unroll
        for (int i = 0; i < 8; ++i) ss += red[i];
        red[0] = ss;
    }
    __syncthreads();
    s = red[0];

    float w0 = actw[0], w1 = actw[1], w2 = actw[2];
    float val = w0 * fmaxf(acc, 0.f)
              + w1 * (1.f / (1.f + __expf(-acc)))
              + w2 * (e / s);
    scale[b * C_ + c] = val;
}

// ---------------------------------------------------------------------------
// Kernel 4 (MFMA, round-6 structure + FULL fragment hoist):
// one GEMM  M=2560, N=8192 (b*512+c), K=1280
//   C[g,n] = sum_k G3w[g,k] * X[b, k/256, c, k%256],  n = b*512+c
//   out[b, g>>8, c, g&255] = scale[b,c] * (C + g3b[g])
// BM=160 x BN=256 x BK=32, 4 waves (1M x 4N), per-wave 160x64, acc[10][4].
// Grid 512 = EXACTLY 2 blocks/CU -> perfectly balanced, zero tail.
// 2-buffer LDS drain-barrier loop; XCD owns 4 N-tiles x 16 M-tiles.
// NEW: all 14 fragments (b0[4] + a0[10]) loaded into named registers BEFORE
// the pure 40-MFMA cluster -- ds_read latency pipelines behind the 14-deep
// issue burst instead of being exposed per-m inside the cluster. VGPR budget
// ~240 <= 256 allowed by __launch_bounds__(256,2).
// ---------------------------------------------------------------------------
#define BM 160
#define BN 256
#define BK 32
#define NKT (KIN_ / BK)          // 40
#define ABUF (BM * BK)           // 5120 u16 = 10 KB
#define BBUF (BN * BK)           // 8192 u16 = 16 KB
#define BUFU (ABUF + BBUF)       // 13312 u16 = 26 KB

__device__ __forceinline__ void gload16(const void* g, void* l) {
    __builtin_amdgcn_global_load_lds(
        (const __attribute__((address_space(1))) void*)g,
        (__attribute__((address_space(3))) void*)l, 16, 0, 0);
}

__global__ __launch_bounds__(256, 2) void k_gemm_mfma(
    const u16* __restrict__ A,   // bf16 [GOUT_][KIN_]
    const u16* __restrict__ X,   // bf16 [B_][T_][C_][HW_]
    const float* __restrict__ g3b,
    const float* __restrict__ scale,
    float* __restrict__ out)
{
    __shared__ u16 lds[2 * BUFU];            // 52 KiB

    // grid 512 = 8 XCDs x 64: each XCD owns 4 consecutive N-tiles x 16 M-tiles
    int orig = blockIdx.x;
    int xcd  = orig & 7;
    int idx  = orig >> 3;                    // 0..63
    int nt   = xcd * 4 + (idx >> 4);         // 0..31
    int gt   = idx & 15;                     // 0..15
    int g0   = gt * BM;
    int b    = nt >> 1;                      // batch
    int c0   = (nt & 1) * BN;                // col within batch

    int tid = threadIdx.x;
    int lane = tid & 63, wid = tid >> 6;     // 4 waves, 1M x 4N
    int lrow = lane & 15, lslot = lane >> 4;

    // staging geometry (rule #21 pair): chunk q -> row r=q>>2, phys slot
    // p=q&3 (LDS linear at q*8 u16); global src slot s = p ^ ((r>>1)&3)
    int offA0, offA1, offA2, offB0, offB1, offB2, offB3;
    {
        int q, r, p;
        q = tid;        r = q >> 2; p = q & 3; offA0 = r * KIN_ + (p ^ ((r >> 1) & 3)) * 8;
        q = 256 + tid;  r = q >> 2; p = q & 3; offA1 = r * KIN_ + (p ^ ((r >> 1) & 3)) * 8;
        q = 512 + tid;  r = q >> 2; p = q & 3; offA2 = r * KIN_ + (p ^ ((r >> 1) & 3)) * 8;
        q = tid;        r = q >> 2; p = q & 3; offB0 = r * HW_  + (p ^ ((r >> 1) & 3)) * 8;
        q = 256 + tid;  r = q >> 2; p = q & 3; offB1 = r * HW_  + (p ^ ((r >> 1) & 3)) * 8;
        q = 512 + tid;  r = q >> 2; p = q & 3; offB2 = r * HW_  + (p ^ ((r >> 1) & 3)) * 8;
        q = 768 + tid;  r = q >> 2; p = q & 3; offB3 = r * HW_  + (p ^ ((r >> 1) & 3)) * 8;
    }
    int wb = wid * 512;                      // wave-uniform LDS write base (u16)

    const u16* Abase = A + (size_t)g0 * KIN_;
    #define XOFF(kt) ((((size_t)(b * T_ + ((kt) >> 3)) * C_) + c0) * HW_ + ((kt) & 7) * 32)

    #define STAGE(D, sA, sX)                                                 \
    {                                                                        \
        gload16((sA) + offA0, (D) + wb);                                     \
        gload16((sA) + offA1, (D) + 2048 + wb);                              \
        if (tid < 128) gload16((sA) + offA2, (D) + 4096 + wb);               \
        gload16((sX) + offB0, (D) + ABUF + wb);                              \
        gload16((sX) + offB1, (D) + ABUF + 2048 + wb);                       \
        gload16((sX) + offB2, (D) + ABUF + 4096 + wb);                       \
        gload16((sX) + offB3, (D) + ABUF + 6144 + wb);                       \
    }

    // ---- prologue: stage tile 0 into buffer 0
    STAGE(lds, Abase, X + XOFF(0));
    __syncthreads();

    f32x4 acc[10][4];
    #pragma unroll
    for (int m = 0; m < 10; ++m)
        #pragma unroll
        for (int n = 0; n < 4; ++n) acc[m][n] = (f32x4)0.f;

    int cur = 0;
    for (int t = 0; t < NKT; ++t) {
        const u16* Ac = lds + cur * BUFU;
        const u16* Bc = Ac + ABUF;
        if (t + 1 < NKT) {
            u16* Dn = lds + (cur ^ 1) * BUFU;
            const u16* sA = Abase + (size_t)(t + 1) * BK;
            const u16* sX = X + XOFF(t + 1);
            STAGE(Dn, sA, sX);
        }

        // ---- hoist ALL fragments into registers before the MFMA cluster
        s16x8 b0[4];
        #pragma unroll
        for (int n = 0; n < 4; ++n) {
            int r = wid * 64 + n * 16 + lrow;
            int p = lslot ^ ((r >> 1) & 3);
            b0[n] = *reinterpret_cast<const s16x8*>(Bc + r * BK + p * 8);
        }
        s16x8 a0[10];
        #pragma unroll
        for (int m = 0; m < 10; ++m) {
            int r = m * 16 + lrow;
            int p = lslot ^ ((r >> 1) & 3);
            a0[m] = *reinterpret_cast<const s16x8*>(Ac + r * BK + p * 8);
        }

        __builtin_amdgcn_s_setprio(1);
        #pragma unroll
        for (int m = 0; m < 10; ++m)
            #pragma unroll
            for (int n = 0; n < 4; ++n)
                acc[m][n] = __builtin_amdgcn_mfma_f32_16x16x32_bf16(
                                a0[m], b0[n], acc[m][n], 0, 0, 0);
        __builtin_amdgcn_s_setprio(0);

        __syncthreads();   // drains vmcnt+lgkmcnt: next tile resident,
                           // cur buffer reads complete before re-stage
        cur ^= 1;
    }

    // ---- epilogue: D row -> g, col -> c  (validated m89 layout)
    int cb = c0 + wid * 64;
    #pragma unroll
    for (int n = 0; n < 4; ++n) {
        int c = cb + n * 16 + lrow;
        float sc = scale[b * C_ + c];
        #pragma unroll
        for (int m = 0; m < 10; ++m) {
            int g  = g0 + m * 16 + lslot * 4;   // 4-aligned
            int f  = g >> 8;
            int hw = g & 255;
            float4 bias = *reinterpret_cast<const float4*>(g3b + g);
            f32x4 v = acc[m][n];
            float4 o;
            o.x = sc * (v[0] + bias.x);
            o.y = sc * (v[1] + bias.y);
            o.z = sc * (v[2] + bias.z);
            o.w = sc * (v[3] + bias.w);
            *reinterpret_cast<float4*>(
                out + (((size_t)(b * NF_ + f) * C_ + c) * HW_ + hw)) = o;
        }
    }
    #undef XOFF
    #undef STAGE
}

// ---------------------------------------------------------------------------
// Fallback fp32 GEMM (round-1, known-correct) in case ws_size is too small
// ---------------------------------------------------------------------------
#define FBM 128
#define FBN 128
#define FBK 32
__global__ __launch_bounds__(256) void k_gemm_fp32(
    const float* __restrict__ in,
    const float* __restrict__ g3w,
    const float* __restrict__ g3b,
    const float* __restrict__ scale,
    float* __restrict__ out)
{
    int b  = blockIdx.y;
    int gt = blockIdx.x >> 2;
    int ct = blockIdx.x & 3;
    int g0 = gt * FBM, c0 = ct * FBN;
    int tid = threadIdx.x;
    int ty = tid & 15;
    int tx = tid >> 4;

    __shared__ float As[FBK][FBM + 4];
    __shared__ float Bs[FBK][FBN + 4];

    float acc[8][8];
    #pragma unroll
    for (int i = 0; i < 8; ++i)
        #pragma unroll
        for (int j = 0; j < 8; ++j) acc[i][j] = 0.f;

    for (int k0 = 0; k0 < KIN_; k0 += FBK) {
        int t   = k0 >> 8;
        int hw0 = k0 & 255;
        #pragma unroll
        for (int p = 0; p < 16; ++p) {
            int idx = tid + p * 256;
            int kk = idx & 31, gg = idx >> 5;
            As[kk][gg] = g3w[(size_t)(g0 + gg) * KIN_ + k0 + kk];
        }
        const float* bsrc = in + ((size_t)(b * T_ + t) * C_ + c0) * HW_ + hw0;
        #pragma unroll
        for (int p = 0; p < 16; ++p) {
            int idx = tid + p * 256;
            int kk = idx & 31, cc = idx >> 5;
            Bs[kk][cc] = bsrc[(size_t)cc * HW_ + kk];
        }
        __syncthreads();
        #pragma unroll
        for (int kk = 0; kk < FBK; ++kk) {
            float a[8], bb[8];
            #pragma unroll
            for (int i = 0; i < 8; ++i) a[i] = As[kk][ty * 8 + i];
            #pragma unroll
            for (int j = 0; j < 8; ++j) bb[j] = Bs[kk][tx * 8 + j];
            #pragma unroll
            for (int i = 0; i < 8; ++i)
                #pragma unroll
                for (int j = 0; j < 8; ++j)
                    acc[i][j] = fmaf(a[i], bb[j], acc[i][j]);
        }
        __syncthreads();
    }

    int gl = ty * 8;
    int g  = g0 + gl;
    int f  = g >> 8;
    int hw = g & 255;
    #pragma unroll
    for (int j = 0; j < 8; ++j) {
        int c = c0 + tx * 8 + j;
        float sc = scale[b * C_ + c];
        float* op = out + (((size_t)(b * NF_ + f) * C_ + c) * HW_ + hw);
        float4 v0, v1;
        v0.x = sc * (acc[0][j] + g3b[g + 0]);
        v0.y = sc * (acc[1][j] + g3b[g + 1]);
        v0.z = sc * (acc[2][j] + g3b[g + 2]);
        v0.w = sc * (acc[3][j] + g3b[g + 3]);
        v1.x = sc * (acc[4][j] + g3b[g + 4]);
        v1.y = sc * (acc[5][j] + g3b[g + 5]);
        v1.z = sc * (acc[6][j] + g3b[g + 6]);
        v1.w = sc * (acc[7][j] + g3b[g + 7]);
        reinterpret_cast<float4*>(op)[0] = v0;
        reinterpret_cast<float4*>(op)[1] = v1;
    }
}

// ---------------------------------------------------------------------------
extern "C" void kernel_launch(void* const* d_in, const int* in_sizes, int n_in,
                              void* d_out, int out_size, void* d_ws, size_t ws_size,
                              hipStream_t stream) {
    const float* input    = (const float*)d_in[0];
    const float* actw     = (const float*)d_in[2];
    const float* conv1_w  = (const float*)d_in[3];
    const float* conv1_b  = (const float*)d_in[4];
    const float* g3w      = (const float*)d_in[5];
    const float* g3b      = (const float*)d_in[6];
    const float* ffnn1_w  = (const float*)d_in[7];
    const float* ffnn1_b  = (const float*)d_in[8];
    float* out = (float*)d_out;

    float* ws     = (float*)d_ws;
    float* wbar   = ws;                    // 1280
    float* bbar   = ws + KIN_;             // 1
    float* pooled = ws + 1536;             // 8192
    float* scale  = ws + 1536 + B_ * C_;   // 8192 (fallback: "pre"/scale)
    u16* wsA = (u16*)(ws + 17920);                       // 2560*1280 bf16
    u16* wsX = wsA + (size_t)GOUT_ * KIN_;               // 16*5*512*256 bf16
    const size_t need = 71680ull + (size_t)GOUT_ * KIN_ * 2 + (size_t)B_ * T_ * C_ * HW_ * 2;

    if (ws_size >= need) {
        k_init<<<dim3(5 + CASTW_BLKS), dim3(256), 0, stream>>>(
            conv1_w, conv1_b, wbar, bbar, g3w, wsA);
        k_prep<<<dim3(FUSE_BLKS), dim3(256), 0, stream>>>(
            input, wbar, bbar, pooled, wsX);
        k_prescale<<<dim3(B_), dim3(512), 0, stream>>>(
            pooled, ffnn1_w, ffnn1_b, actw, scale);
        k_gemm_mfma<<<dim3(512), dim3(256), 0, stream>>>(
            wsA, wsX, g3b, scale, out);
    } else {
        k_wbar<<<dim3((KIN_ + 255) / 256), dim3(256), 0, stream>>>(conv1_w, conv1_b, wbar, bbar);
        k_pooled<<<dim3(B_ * C_), dim3(256), 0, stream>>>(input, wbar, bbar, pooled);
        k_scale<<<dim3(B_), dim3(512), 0, stream>>>(pooled, ffnn1_w, ffnn1_b, actw, scale);
        k_gemm_fp32<<<dim3((GOUT_ / FBM) * (C_ / FBN), B_), dim3(256), 0, stream>>>(
            input, g3w, g3b, scale, out);
    }
}

// Round 12
// 91.569 us; speedup vs baseline: 1.3501x; 1.3501x over previous
//
#include <hip/hip_runtime.h>
#include <hip/hip_bf16.h>
#include <stdint.h>

// Problem constants
#define B_   16
#define T_   5
#define C_   512
#define HW_  256          // H*W
#define NF_  10
#define KIN_ 1280         // T*H*W
#define GOUT_ 2560        // NF*H*W

typedef __attribute__((ext_vector_type(8))) short s16x8;
typedef __attribute__((ext_vector_type(4))) float f32x4;
typedef unsigned short u16;

__device__ __forceinline__ u16 f2bf(float x) {
    unsigned int u = __float_as_uint(x);
    return (u16)((u + 0x7FFFu + ((u >> 16) & 1u)) >> 16);
}

// ---------------------------------------------------------------------------
// Kernel 0 (merged init): blocks 0..4: wbar[k] = mean_f conv1_w[f,k] (+bbar)
//                         blocks 5..1604: G3 weight fp32->bf16 cast
// ---------------------------------------------------------------------------
#define CASTW_N8  (GOUT_ * KIN_ / 8) // 409600
#define CASTW_BLKS (CASTW_N8 / 256)  // 1600

__global__ __launch_bounds__(256) void k_init(const float* __restrict__ conv1_w,
                        const float* __restrict__ conv1_b,
                        float* __restrict__ wbar, float* __restrict__ bbar,
                        const float* __restrict__ g3w,
                        u16* __restrict__ wsA) {
    if (blockIdx.x < 5) {
        int k = blockIdx.x * 256 + threadIdx.x;   // 5*256 = 1280 exactly
        float s = 0.f;
        #pragma unroll
        for (int f = 0; f < NF_; ++f) s += conv1_w[f * KIN_ + k];
        wbar[k] = s * (1.0f / NF_);
        if (blockIdx.x == 0 && threadIdx.x == 0) {
            float sb = 0.f;
            #pragma unroll
            for (int f = 0; f < NF_; ++f) sb += conv1_b[f];
            *bbar = sb * (1.0f / NF_);
        }
        return;
    }
    int i = (blockIdx.x - 5) * 256 + threadIdx.x;
    if (i < CASTW_N8) {
        const float4* s = reinterpret_cast<const float4*>(g3w) + (size_t)i * 2;
        float4 v0 = s[0], v1 = s[1];
        union { u16 h[8]; int4 v; } u;
        u.h[0] = f2bf(v0.x); u.h[1] = f2bf(v0.y); u.h[2] = f2bf(v0.z); u.h[3] = f2bf(v0.w);
        u.h[4] = f2bf(v1.x); u.h[5] = f2bf(v1.y); u.h[6] = f2bf(v1.z); u.h[7] = f2bf(v1.w);
        reinterpret_cast<int4*>(wsA)[i] = u.v;
    }
}

// fallback-path wbar-only kernel
__global__ void k_wbar(const float* __restrict__ conv1_w,
                       const float* __restrict__ conv1_b,
                       float* __restrict__ wbar, float* __restrict__ bbar) {
    int k = blockIdx.x * blockDim.x + threadIdx.x;
    if (k < KIN_) {
        float s = 0.f;
        #pragma unroll
        for (int f = 0; f < NF_; ++f) s += conv1_w[f * KIN_ + k];
        wbar[k] = s * (1.0f / NF_);
    }
    if (blockIdx.x == 0 && threadIdx.x == 0) {
        float s = 0.f;
        #pragma unroll
        for (int f = 0; f < NF_; ++f) s += conv1_b[f];
        *bbar = s * (1.0f / NF_);
    }
}

// ---------------------------------------------------------------------------
// Kernel 1: pooled[b,c] + input->bf16 cast (single pass; 160 threads x 8)
// ---------------------------------------------------------------------------
#define FUSE_BLKS (B_ * C_)          // 8192

__global__ __launch_bounds__(256) void k_prep(const float* __restrict__ in,
                         const float* __restrict__ wbar,
                         const float* __restrict__ bbar,
                         float* __restrict__ pooled,
                         u16* __restrict__ X) {
    int bc = blockIdx.x;            // 0 .. B*C-1
    int b = bc >> 9;
    int c = bc & 511;
    int tid = threadIdx.x;

    float s = 0.f;
    if (tid < 160) {
        int t   = tid >> 5;          // 0..4
        int hw0 = (tid & 31) * 8;    // 0..248
        size_t off = ((size_t)(b * T_ + t) * C_ + c) * HW_ + hw0;
        const float4* ip = reinterpret_cast<const float4*>(in + off);
        float4 v0 = ip[0], v1 = ip[1];
        const float4* wp = reinterpret_cast<const float4*>(wbar + t * HW_ + hw0);
        float4 w0 = wp[0], w1 = wp[1];
        s = v0.x * w0.x + v0.y * w0.y + v0.z * w0.z + v0.w * w0.w
          + v1.x * w1.x + v1.y * w1.y + v1.z * w1.z + v1.w * w1.w;
        union { u16 h[8]; int4 q; } u;
        u.h[0] = f2bf(v0.x); u.h[1] = f2bf(v0.y); u.h[2] = f2bf(v0.z); u.h[3] = f2bf(v0.w);
        u.h[4] = f2bf(v1.x); u.h[5] = f2bf(v1.y); u.h[6] = f2bf(v1.z); u.h[7] = f2bf(v1.w);
        reinterpret_cast<int4*>(X + off)[0] = u.q;
    }

    #pragma unroll
    for (int off = 32; off > 0; off >>= 1) s += __shfl_down(s, off, 64);
    __shared__ float red[4];
    int wid = tid >> 6, lane = tid & 63;
    if (lane == 0) red[wid] = s;
    __syncthreads();
    if (tid == 0) {
        float tot = red[0] + red[1] + red[2] + red[3];
        pooled[bc] = tot + *bbar;
    }
}

// non-fused fallback (small-ws path)
__global__ __launch_bounds__(256) void k_pooled(const float* __restrict__ in,
                         const float* __restrict__ wbar,
                         const float* __restrict__ bbar,
                         float* __restrict__ pooled) {
    int bc = blockIdx.x;
    int b = bc >> 9;
    int c = bc & 511;
    int hw = threadIdx.x;
    const float* base = in + ((size_t)(b * T_) * C_ + c) * HW_;
    float s = 0.f;
    #pragma unroll
    for (int t = 0; t < T_; ++t)
        s = fmaf(wbar[t * HW_ + hw], base[(size_t)t * C_ * HW_ + hw], s);
    #pragma unroll
    for (int off = 32; off > 0; off >>= 1) s += __shfl_down(s, off, 64);
    __shared__ float red[4];
    int wid = threadIdx.x >> 6, lane = threadIdx.x & 63;
    if (lane == 0) red[wid] = s;
    __syncthreads();
    if (threadIdx.x == 0) {
        float tot = red[0] + red[1] + red[2] + red[3];
        pooled[bc] = tot + *bbar;
    }
}

// ---------------------------------------------------------------------------
// Kernel 2 (round-10 proven): pre[b,c] = pooled[b,:].ffnn1_w[c,:] + b[c]
// 256 blocks: b = bx>>4, grp = bx&15 -> 32 rows. 4 waves x 8 rows, coalesced.
// ---------------------------------------------------------------------------
__global__ __launch_bounds__(256) void k_pre(const float* __restrict__ pooled,
                       const float* __restrict__ ffnn1_w,
                       const float* __restrict__ ffnn1_b,
                       float* __restrict__ pre) {
    int b   = blockIdx.x >> 4;
    int grp = blockIdx.x & 15;
    int wid = threadIdx.x >> 6, lane = threadIdx.x & 63;

    const float4* pp = reinterpret_cast<const float4*>(pooled + b * C_ + lane * 8);
    float4 pa = pp[0], pb = pp[1];

    #pragma unroll
    for (int rr = 0; rr < 8; ++rr) {
        int c = grp * 32 + wid * 8 + rr;
        const float4* wr = reinterpret_cast<const float4*>(ffnn1_w + (size_t)c * C_ + lane * 8);
        float4 wa = wr[0], wb2 = wr[1];
        float d = pa.x * wa.x + pa.y * wa.y + pa.z * wa.z + pa.w * wa.w
                + pb.x * wb2.x + pb.y * wb2.y + pb.z * wb2.z + pb.w * wb2.w;
        #pragma unroll
        for (int off = 32; off > 0; off >>= 1) d += __shfl_xor(d, off, 64);
        if (lane == 0) pre[b * C_ + c] = d + ffnn1_b[c];
    }
}

// ---------------------------------------------------------------------------
// Kernel 3 (round-10 proven): scale from pre (softmax + 3 activations)
// ---------------------------------------------------------------------------
__global__ __launch_bounds__(512) void k_act(const float* __restrict__ pre,
                       const float* __restrict__ actw,
                       float* __restrict__ scale) {
    int b = blockIdx.x;
    int tid = threadIdx.x;          // 0..511
    int wid = tid >> 6, lane = tid & 63;
    __shared__ float redm[8], reds[8];

    float p0 = pre[b * C_ + tid];
    float mx = p0;
    #pragma unroll
    for (int off = 32; off > 0; off >>= 1) mx = fmaxf(mx, __shfl_xor(mx, off, 64));
    if (lane == 0) redm[wid] = mx;
    __syncthreads();
    float m8 = redm[0];
    #pragma unroll
    for (int i = 1; i < 8; ++i) m8 = fmaxf(m8, redm[i]);
    float e0 = __expf(p0 - m8);
    float sm = e0;
    #pragma unroll
    for (int off = 32; off > 0; off >>= 1) sm += __shfl_xor(sm, off, 64);
    if (lane == 0) reds[wid] = sm;
    __syncthreads();
    float ssum = reds[0];
    #pragma unroll
    for (int i = 1; i < 8; ++i) ssum += reds[i];

    float aw0 = actw[0], aw1 = actw[1], aw2 = actw[2];
    scale[b * C_ + tid] = aw0 * fmaxf(p0, 0.f)
                        + aw1 * (1.f / (1.f + __expf(-p0)))
                        + aw2 * (e0 / ssum);
}

// ---------------------------------------------------------------------------
// Fallback-path scale kernel (original, from pooled)
// ---------------------------------------------------------------------------
__global__ __launch_bounds__(512) void k_scale(const float* __restrict__ pooled,
                        const float* __restrict__ ffnn1_w,
                        const float* __restrict__ ffnn1_b,
                        const float* __restrict__ actw,
                        float* __restrict__ scale) {
    int b = blockIdx.x;
    int c = threadIdx.x;
    __shared__ float sp[C_];
    __shared__ float red[8];

    sp[c] = pooled[b * C_ + c];
    __syncthreads();

    float acc = ffnn1_b[c];
    const float* wr = ffnn1_w + (size_t)c * C_;
    #pragma unroll 8
    for (int j = 0; j < C_; ++j) acc = fmaf(wr[j], sp[j], acc);

    int wid = c >> 6, lane = c & 63;
    float m = acc;
    #pragma unroll
    for (int off = 32; off > 0; off >>= 1) m = fmaxf(m, __shfl_down(m, off, 64));
    if (lane == 0) red[wid] = m;
    __syncthreads();
    if (c == 0) {
        float mm = red[0];
        #pragma unroll
        for (int i = 1; i < 8; ++i) mm = fmaxf(mm, red[i]);
        red[0] = mm;
    }
    __syncthreads();
    m = red[0];
    __syncthreads();

    float e = __expf(acc - m);
    float s = e;
    #pragma unroll
    for (int off = 32; off > 0; off >>= 1) s += __shfl_down(s, off, 64);
    if (lane == 0) red[wid] = s;
    __syncthreads();
    if (c == 0) {
        float ss = 0.f;
        #pragma unroll
        for (int i = 0; i < 8; ++i) ss += red[i];
        red[0] = ss;
    }
    __syncthreads();
    s = red[0];

    float w0 = actw[0], w1 = actw[1], w2 = actw[2];
    float val = w0 * fmaxf(acc, 0.f)
              + w1 * (1.f / (1.f + __expf(-acc)))
              + w2 * (e / s);
    scale[b * C_ + c] = val;
}

// ---------------------------------------------------------------------------
// Kernel 4 (MFMA v7, BK=64 two-plane): one GEMM M=2560, N=8192, K=1280
//   C[g,n] = sum_k G3w[g,k] * X[b, k/256, c, k%256],  n = b*512+c
//   out[b, g>>8, c, g&255] = scale[b,c] * (C + g3b[g])
//
// BM=160 x BN=128 x BK=64, 4 waves as 2M x 2N, per-wave 80x64, acc[5][4].
// BK=64 stored as TWO BK=32 planes per operand -> row stride stays 64 B, so
// the verified 0-conflict XOR slot swizzle carries over unchanged.
// 20 K-steps (half the barrier drains of BK=32). ds_reads/thread/step = 18
// (vs 24 if 1Mx4N) -- LDS floor ~29 us vs MFMA floor ~26 us.
// Grid 1024 = exactly 2 rounds of 512 resident blocks (2 blk/CU, 72 KB LDS),
// zero tail. XCD owns 8 N-tiles x 16 M-tiles (X slice 2.6 MB, L2-resident).
// Proven drain-barrier loop (one __syncthreads per step).
// ---------------------------------------------------------------------------
#define BM 160
#define BN 128
#define BK 64
#define NKT (KIN_ / BK)          // 20
#define APL 5120                 // A plane: 160 rows * 32 u16
#define BPL 4096                 // B plane: 128 rows * 32 u16
#define ABUFU (2 * APL)          // 10240 u16
#define BUFU (ABUFU + 2 * BPL)   // 18432 u16 = 36 KB

__device__ __forceinline__ void gload16(const void* g, void* l) {
    __builtin_amdgcn_global_load_lds(
        (const __attribute__((address_space(1))) void*)g,
        (__attribute__((address_space(3))) void*)l, 16, 0, 0);
}

__global__ __launch_bounds__(256, 2) void k_gemm_mfma(
    const u16* __restrict__ A,   // bf16 [GOUT_][KIN_]
    const u16* __restrict__ X,   // bf16 [B_][T_][C_][HW_]
    const float* __restrict__ g3b,
    const float* __restrict__ scale,
    float* __restrict__ out)
{
    __shared__ u16 lds[2 * BUFU];            // 72 KiB

    // grid 1024 = 8 XCDs x 128: each XCD owns 8 N-tiles x 16 M-tiles
    int orig = blockIdx.x;
    int xcd  = orig & 7;
    int idx  = orig >> 3;                    // 0..127
    int nt   = xcd * 8 + (idx >> 4);         // 0..63
    int gt   = idx & 15;                     // 0..15
    int g0   = gt * BM;
    int b    = nt >> 2;                      // batch (4 N-tiles of 128 per b)
    int c0   = (nt & 3) * BN;                // col within batch

    int tid = threadIdx.x;
    int lane = tid & 63, wid = tid >> 6;     // 4 waves: 2M x 2N
    int wr = wid >> 1, wc = wid & 1;
    int lrow = lane & 15, lslot = lane >> 4;

    // staging geometry (rule #21 pair, two-plane): chunk q -> plane, row r,
    // phys slot ps (LDS linear at q*8 u16); global source slot s = ps ^
    // ((r>>1)&3); source elem offset = r*ld + plane*32 + s*8.
    // A: 1280 chunks (5 issues), plane = q>=640. B: 1024 chunks (4 issues),
    // plane = q>>9.
    int offA[5], offB[4];
    #pragma unroll
    for (int i = 0; i < 5; ++i) {
        int q = i * 256 + tid;
        int pl = (q >= 640) ? 1 : 0;
        int rem = q - pl * 640;
        int r = rem >> 2, ps = rem & 3;
        int s = ps ^ ((r >> 1) & 3);
        offA[i] = r * KIN_ + pl * 32 + s * 8;
    }
    #pragma unroll
    for (int i = 0; i < 4; ++i) {
        int q = i * 256 + tid;
        int pl = q >> 9;
        int rem = q & 511;
        int r = rem >> 2, ps = rem & 3;
        int s = ps ^ ((r >> 1) & 3);
        offB[i] = r * HW_ + pl * 32 + s * 8;
    }
    int wb = wid * 512;                      // wave-uniform LDS write base (u16)

    const u16* Abase = A + (size_t)g0 * KIN_;
    // X tile base for K-tile kt (BK=64: 4 K-tiles per t-plane)
    #define XOFF(kt) ((((size_t)(b * T_ + ((kt) >> 2)) * C_) + c0) * HW_ + ((kt) & 3) * 64)

    #define STAGE(D, sA, sX)                                                 \
    {                                                                        \
        gload16((sA) + offA[0], (D) + wb);                                   \
        gload16((sA) + offA[1], (D) + 2048 + wb);                            \
        gload16((sA) + offA[2], (D) + 4096 + wb);                            \
        gload16((sA) + offA[3], (D) + 6144 + wb);                            \
        gload16((sA) + offA[4], (D) + 8192 + wb);                            \
        gload16((sX) + offB[0], (D) + ABUFU + wb);                           \
        gload16((sX) + offB[1], (D) + ABUFU + 2048 + wb);                    \
        gload16((sX) + offB[2], (D) + ABUFU + 4096 + wb);                    \
        gload16((sX) + offB[3], (D) + ABUFU + 6144 + wb);                    \
    }

    // ---- prologue: stage tile 0 into buffer 0
    STAGE(lds, Abase, X + XOFF(0));
    __syncthreads();

    f32x4 acc[5][4];
    #pragma unroll
    for (int m = 0; m < 5; ++m)
        #pragma unroll
        for (int n = 0; n < 4; ++n) acc[m][n] = (f32x4)0.f;

    int cur = 0;
    for (int t = 0; t < NKT; ++t) {
        const u16* Ac = lds + cur * BUFU;
        const u16* Bc = Ac + ABUFU;
        if (t + 1 < NKT) {
            u16* Dn = lds + (cur ^ 1) * BUFU;
            STAGE(Dn, Abase + (size_t)(t + 1) * BK, X + XOFF(t + 1));
        }

        // ---- k-half 0: frags from plane 0
        s16x8 b0[4], a0[5];
        #pragma unroll
        for (int n = 0; n < 4; ++n) {
            int r = wc * 64 + n * 16 + lrow;
            int p = lslot ^ ((r >> 1) & 3);
            b0[n] = *reinterpret_cast<const s16x8*>(Bc + r * 32 + p * 8);
        }
        #pragma unroll
        for (int m = 0; m < 5; ++m) {
            int r = wr * 80 + m * 16 + lrow;
            int p = lslot ^ ((r >> 1) & 3);
            a0[m] = *reinterpret_cast<const s16x8*>(Ac + r * 32 + p * 8);
        }
        __builtin_amdgcn_s_setprio(1);
        #pragma unroll
        for (int m = 0; m < 5; ++m)
            #pragma unroll
            for (int n = 0; n < 4; ++n)
                acc[m][n] = __builtin_amdgcn_mfma_f32_16x16x32_bf16(
                                a0[m], b0[n], acc[m][n], 0, 0, 0);
        __builtin_amdgcn_s_setprio(0);

        // ---- k-half 1: frags from plane 1
        s16x8 b1[4], a1[5];
        #pragma unroll
        for (int n = 0; n < 4; ++n) {
            int r = wc * 64 + n * 16 + lrow;
            int p = lslot ^ ((r >> 1) & 3);
            b1[n] = *reinterpret_cast<const s16x8*>(Bc + BPL + r * 32 + p * 8);
        }
        #pragma unroll
        for (int m = 0; m < 5; ++m) {
            int r = wr * 80 + m * 16 + lrow;
            int p = lslot ^ ((r >> 1) & 3);
            a1[m] = *reinterpret_cast<const s16x8*>(Ac + APL + r * 32 + p * 8);
        }
        __builtin_amdgcn_s_setprio(1);
        #pragma unroll
        for (int m = 0; m < 5; ++m)
            #pragma unroll
            for (int n = 0; n < 4; ++n)
                acc[m][n] = __builtin_amdgcn_mfma_f32_16x16x32_bf16(
                                a1[m], b1[n], acc[m][n], 0, 0, 0);
        __builtin_amdgcn_s_setprio(0);

        __syncthreads();   // drains vmcnt+lgkmcnt: next tile resident,
                           // cur buffer reads complete before re-stage
        cur ^= 1;
    }

    // ---- epilogue: D row -> g, col -> c  (validated m89 layout)
    #pragma unroll
    for (int n = 0; n < 4; ++n) {
        int c = c0 + wc * 64 + n * 16 + lrow;
        float sc = scale[b * C_ + c];
        #pragma unroll
        for (int m = 0; m < 5; ++m) {
            int g  = g0 + wr * 80 + m * 16 + lslot * 4;   // 4-aligned
            int f  = g >> 8;
            int hw = g & 255;
            float4 bias = *reinterpret_cast<const float4*>(g3b + g);
            f32x4 v = acc[m][n];
            float4 o;
            o.x = sc * (v[0] + bias.x);
            o.y = sc * (v[1] + bias.y);
            o.z = sc * (v[2] + bias.z);
            o.w = sc * (v[3] + bias.w);
            *reinterpret_cast<float4*>(
                out + (((size_t)(b * NF_ + f) * C_ + c) * HW_ + hw)) = o;
        }
    }
    #undef XOFF
    #undef STAGE
}

// ---------------------------------------------------------------------------
// Fallback fp32 GEMM (round-1, known-correct) in case ws_size is too small
// ---------------------------------------------------------------------------
#define FBM 128
#define FBN 128
#define FBK 32
__global__ __launch_bounds__(256) void k_gemm_fp32(
    const float* __restrict__ in,
    const float* __restrict__ g3w,
    const float* __restrict__ g3b,
    const float* __restrict__ scale,
    float* __restrict__ out)
{
    int b  = blockIdx.y;
    int gt = blockIdx.x >> 2;
    int ct = blockIdx.x & 3;
    int g0 = gt * FBM, c0 = ct * FBN;
    int tid = threadIdx.x;
    int ty = tid & 15;
    int tx = tid >> 4;

    __shared__ float As[FBK][FBM + 4];
    __shared__ float Bs[FBK][FBN + 4];

    float acc[8][8];
    #pragma unroll
    for (int i = 0; i < 8; ++i)
        #pragma unroll
        for (int j = 0; j < 8; ++j) acc[i][j] = 0.f;

    for (int k0 = 0; k0 < KIN_; k0 += FBK) {
        int t   = k0 >> 8;
        int hw0 = k0 & 255;
        #pragma unroll
        for (int p = 0; p < 16; ++p) {
            int idx = tid + p * 256;
            int kk = idx & 31, gg = idx >> 5;
            As[kk][gg] = g3w[(size_t)(g0 + gg) * KIN_ + k0 + kk];
        }
        const float* bsrc = in + ((size_t)(b * T_ + t) * C_ + c0) * HW_ + hw0;
        #pragma unroll
        for (int p = 0; p < 16; ++p) {
            int idx = tid + p * 256;
            int kk = idx & 31, cc = idx >> 5;
            Bs[kk][cc] = bsrc[(size_t)cc * HW_ + kk];
        }
        __syncthreads();
        #pragma unroll
        for (int kk = 0; kk < FBK; ++kk) {
            float a[8], bb[8];
            #pragma unroll
            for (int i = 0; i < 8; ++i) a[i] = As[kk][ty * 8 + i];
            #pragma unroll
            for (int j = 0; j < 8; ++j) bb[j] = Bs[kk][tx * 8 + j];
            #pragma unroll
            for (int i = 0; i < 8; ++i)
                #pragma unroll
                for (int j = 0; j < 8; ++j)
                    acc[i][j] = fmaf(a[i], bb[j], acc[i][j]);
        }
        __syncthreads();
    }

    int gl = ty * 8;
    int g  = g0 + gl;
    int f  = g >> 8;
    int hw = g & 255;
    #pragma unroll
    for (int j = 0; j < 8; ++j) {
        int c = c0 + tx * 8 + j;
        float sc = scale[b * C_ + c];
        float* op = out + (((size_t)(b * NF_ + f) * C_ + c) * HW_ + hw);
        float4 v0, v1;
        v0.x = sc * (acc[0][j] + g3b[g + 0]);
        v0.y = sc * (acc[1][j] + g3b[g + 1]);
        v0.z = sc * (acc[2][j] + g3b[g + 2]);
        v0.w = sc * (acc[3][j] + g3b[g + 3]);
        v1.x = sc * (acc[4][j] + g3b[g + 4]);
        v1.y = sc * (acc[5][j] + g3b[g + 5]);
        v1.z = sc * (acc[6][j] + g3b[g + 6]);
        v1.w = sc * (acc[7][j] + g3b[g + 7]);
        reinterpret_cast<float4*>(op)[0] = v0;
        reinterpret_cast<float4*>(op)[1] = v1;
    }
}

// ---------------------------------------------------------------------------
extern "C" void kernel_launch(void* const* d_in, const int* in_sizes, int n_in,
                              void* d_out, int out_size, void* d_ws, size_t ws_size,
                              hipStream_t stream) {
    const float* input    = (const float*)d_in[0];
    const float* actw     = (const float*)d_in[2];
    const float* conv1_w  = (const float*)d_in[3];
    const float* conv1_b  = (const float*)d_in[4];
    const float* g3w      = (const float*)d_in[5];
    const float* g3b      = (const float*)d_in[6];
    const float* ffnn1_w  = (const float*)d_in[7];
    const float* ffnn1_b  = (const float*)d_in[8];
    float* out = (float*)d_out;

    float* ws     = (float*)d_ws;
    float* wbar   = ws;                    // 1280
    float* bbar   = ws + KIN_;             // 1
    float* pooled = ws + 1536;             // 8192 (reused as scale after k_pre)
    float* pre    = ws + 1536 + B_ * C_;   // 8192
    float* scale  = pooled;                // pooled dead after k_pre -> reuse
    u16* wsA = (u16*)(ws + 17920);                       // 2560*1280 bf16
    u16* wsX = wsA + (size_t)GOUT_ * KIN_;               // 16*5*512*256 bf16
    const size_t need = 71680ull + (size_t)GOUT_ * KIN_ * 2 + (size_t)B_ * T_ * C_ * HW_ * 2;

    if (ws_size >= need) {
        k_init<<<dim3(5 + CASTW_BLKS), dim3(256), 0, stream>>>(
            conv1_w, conv1_b, wbar, bbar, g3w, wsA);
        k_prep<<<dim3(FUSE_BLKS), dim3(256), 0, stream>>>(
            input, wbar, bbar, pooled, wsX);
        k_pre<<<dim3(256), dim3(256), 0, stream>>>(pooled, ffnn1_w, ffnn1_b, pre);
        k_act<<<dim3(B_), dim3(512), 0, stream>>>(pre, actw, scale);
        k_gemm_mfma<<<dim3(1024), dim3(256), 0, stream>>>(
            wsA, wsX, g3b, scale, out);
    } else {
        k_wbar<<<dim3((KIN_ + 255) / 256), dim3(256), 0, stream>>>(conv1_w, conv1_b, wbar, bbar);
        k_pooled<<<dim3(B_ * C_), dim3(256), 0, stream>>>(input, wbar, bbar, pooled);
        k_scale<<<dim3(B_), dim3(512), 0, stream>>>(pooled, ffnn1_w, ffnn1_b, actw, pre);
        k_gemm_fp32<<<dim3((GOUT_ / FBM) * (C_ / FBN), B_), dim3(256), 0, stream>>>(
            input, g3w, g3b, pre, out);
    }
}

// Round 13
// 86.189 us; speedup vs baseline: 1.4343x; 1.0624x over previous
//
#include <hip/hip_runtime.h>
#include <hip/hip_bf16.h>
#include <stdint.h>

// Problem constants
#define B_   16
#define T_   5
#define C_   512
#define HW_  256          // H*W
#define NF_  10
#define KIN_ 1280         // T*H*W
#define GOUT_ 2560        // NF*H*W

typedef __attribute__((ext_vector_type(8))) short s16x8;
typedef __attribute__((ext_vector_type(4))) float f32x4;
typedef unsigned short u16;

__device__ __forceinline__ u16 f2bf(float x) {
    unsigned int u = __float_as_uint(x);
    return (u16)((u + 0x7FFFu + ((u >> 16) & 1u)) >> 16);
}

// ---------------------------------------------------------------------------
// Kernel 0 (merged init): blocks 0..4: wbar[k] = mean_f conv1_w[f,k] (+bbar)
//                         blocks 5..1604: G3 weight fp32->bf16 cast
// ---------------------------------------------------------------------------
#define CASTW_N8  (GOUT_ * KIN_ / 8) // 409600
#define CASTW_BLKS (CASTW_N8 / 256)  // 1600

__global__ __launch_bounds__(256) void k_init(const float* __restrict__ conv1_w,
                        const float* __restrict__ conv1_b,
                        float* __restrict__ wbar, float* __restrict__ bbar,
                        const float* __restrict__ g3w,
                        u16* __restrict__ wsA) {
    if (blockIdx.x < 5) {
        int k = blockIdx.x * 256 + threadIdx.x;   // 5*256 = 1280 exactly
        float s = 0.f;
        #pragma unroll
        for (int f = 0; f < NF_; ++f) s += conv1_w[f * KIN_ + k];
        wbar[k] = s * (1.0f / NF_);
        if (blockIdx.x == 0 && threadIdx.x == 0) {
            float sb = 0.f;
            #pragma unroll
            for (int f = 0; f < NF_; ++f) sb += conv1_b[f];
            *bbar = sb * (1.0f / NF_);
        }
        return;
    }
    int i = (blockIdx.x - 5) * 256 + threadIdx.x;
    if (i < CASTW_N8) {
        const float4* s = reinterpret_cast<const float4*>(g3w) + (size_t)i * 2;
        float4 v0 = s[0], v1 = s[1];
        union { u16 h[8]; int4 v; } u;
        u.h[0] = f2bf(v0.x); u.h[1] = f2bf(v0.y); u.h[2] = f2bf(v0.z); u.h[3] = f2bf(v0.w);
        u.h[4] = f2bf(v1.x); u.h[5] = f2bf(v1.y); u.h[6] = f2bf(v1.z); u.h[7] = f2bf(v1.w);
        reinterpret_cast<int4*>(wsA)[i] = u.v;
    }
}

// fallback-path wbar-only kernel
__global__ void k_wbar(const float* __restrict__ conv1_w,
                       const float* __restrict__ conv1_b,
                       float* __restrict__ wbar, float* __restrict__ bbar) {
    int k = blockIdx.x * blockDim.x + threadIdx.x;
    if (k < KIN_) {
        float s = 0.f;
        #pragma unroll
        for (int f = 0; f < NF_; ++f) s += conv1_w[f * KIN_ + k];
        wbar[k] = s * (1.0f / NF_);
    }
    if (blockIdx.x == 0 && threadIdx.x == 0) {
        float s = 0.f;
        #pragma unroll
        for (int f = 0; f < NF_; ++f) s += conv1_b[f];
        *bbar = s * (1.0f / NF_);
    }
}

// ---------------------------------------------------------------------------
// Kernel 1: pooled[b,c] + input->bf16 cast (single pass; 160 threads x 8)
// ---------------------------------------------------------------------------
#define FUSE_BLKS (B_ * C_)          // 8192

__global__ __launch_bounds__(256) void k_prep(const float* __restrict__ in,
                         const float* __restrict__ wbar,
                         const float* __restrict__ bbar,
                         float* __restrict__ pooled,
                         u16* __restrict__ X) {
    int bc = blockIdx.x;            // 0 .. B*C-1
    int b = bc >> 9;
    int c = bc & 511;
    int tid = threadIdx.x;

    float s = 0.f;
    if (tid < 160) {
        int t   = tid >> 5;          // 0..4
        int hw0 = (tid & 31) * 8;    // 0..248
        size_t off = ((size_t)(b * T_ + t) * C_ + c) * HW_ + hw0;
        const float4* ip = reinterpret_cast<const float4*>(in + off);
        float4 v0 = ip[0], v1 = ip[1];
        const float4* wp = reinterpret_cast<const float4*>(wbar + t * HW_ + hw0);
        float4 w0 = wp[0], w1 = wp[1];
        s = v0.x * w0.x + v0.y * w0.y + v0.z * w0.z + v0.w * w0.w
          + v1.x * w1.x + v1.y * w1.y + v1.z * w1.z + v1.w * w1.w;
        union { u16 h[8]; int4 q; } u;
        u.h[0] = f2bf(v0.x); u.h[1] = f2bf(v0.y); u.h[2] = f2bf(v0.z); u.h[3] = f2bf(v0.w);
        u.h[4] = f2bf(v1.x); u.h[5] = f2bf(v1.y); u.h[6] = f2bf(v1.z); u.h[7] = f2bf(v1.w);
        reinterpret_cast<int4*>(X + off)[0] = u.q;
    }

    #pragma unroll
    for (int off = 32; off > 0; off >>= 1) s += __shfl_down(s, off, 64);
    __shared__ float red[4];
    int wid = tid >> 6, lane = tid & 63;
    if (lane == 0) red[wid] = s;
    __syncthreads();
    if (tid == 0) {
        float tot = red[0] + red[1] + red[2] + red[3];
        pooled[bc] = tot + *bbar;
    }
}

// non-fused fallback (small-ws path)
__global__ __launch_bounds__(256) void k_pooled(const float* __restrict__ in,
                         const float* __restrict__ wbar,
                         const float* __restrict__ bbar,
                         float* __restrict__ pooled) {
    int bc = blockIdx.x;
    int b = bc >> 9;
    int c = bc & 511;
    int hw = threadIdx.x;
    const float* base = in + ((size_t)(b * T_) * C_ + c) * HW_;
    float s = 0.f;
    #pragma unroll
    for (int t = 0; t < T_; ++t)
        s = fmaf(wbar[t * HW_ + hw], base[(size_t)t * C_ * HW_ + hw], s);
    #pragma unroll
    for (int off = 32; off > 0; off >>= 1) s += __shfl_down(s, off, 64);
    __shared__ float red[4];
    int wid = threadIdx.x >> 6, lane = threadIdx.x & 63;
    if (lane == 0) red[wid] = s;
    __syncthreads();
    if (threadIdx.x == 0) {
        float tot = red[0] + red[1] + red[2] + red[3];
        pooled[bc] = tot + *bbar;
    }
}

// ---------------------------------------------------------------------------
// Kernel 2 (round-10 proven): pre[b,c] = pooled[b,:].ffnn1_w[c,:] + b[c]
// 256 blocks: b = bx>>4, grp = bx&15 -> 32 rows. 4 waves x 8 rows, coalesced.
// ---------------------------------------------------------------------------
__global__ __launch_bounds__(256) void k_pre(const float* __restrict__ pooled,
                       const float* __restrict__ ffnn1_w,
                       const float* __restrict__ ffnn1_b,
                       float* __restrict__ pre) {
    int b   = blockIdx.x >> 4;
    int grp = blockIdx.x & 15;
    int wid = threadIdx.x >> 6, lane = threadIdx.x & 63;

    const float4* pp = reinterpret_cast<const float4*>(pooled + b * C_ + lane * 8);
    float4 pa = pp[0], pb = pp[1];

    #pragma unroll
    for (int rr = 0; rr < 8; ++rr) {
        int c = grp * 32 + wid * 8 + rr;
        const float4* wr = reinterpret_cast<const float4*>(ffnn1_w + (size_t)c * C_ + lane * 8);
        float4 wa = wr[0], wb2 = wr[1];
        float d = pa.x * wa.x + pa.y * wa.y + pa.z * wa.z + pa.w * wa.w
                + pb.x * wb2.x + pb.y * wb2.y + pb.z * wb2.z + pb.w * wb2.w;
        #pragma unroll
        for (int off = 32; off > 0; off >>= 1) d += __shfl_xor(d, off, 64);
        if (lane == 0) pre[b * C_ + c] = d + ffnn1_b[c];
    }
}

// ---------------------------------------------------------------------------
// Kernel 3 (round-10 proven): scale from pre (softmax + 3 activations)
// ---------------------------------------------------------------------------
__global__ __launch_bounds__(512) void k_act(const float* __restrict__ pre,
                       const float* __restrict__ actw,
                       float* __restrict__ scale) {
    int b = blockIdx.x;
    int tid = threadIdx.x;          // 0..511
    int wid = tid >> 6, lane = tid & 63;
    __shared__ float redm[8], reds[8];

    float p0 = pre[b * C_ + tid];
    float mx = p0;
    #pragma unroll
    for (int off = 32; off > 0; off >>= 1) mx = fmaxf(mx, __shfl_xor(mx, off, 64));
    if (lane == 0) redm[wid] = mx;
    __syncthreads();
    float m8 = redm[0];
    #pragma unroll
    for (int i = 1; i < 8; ++i) m8 = fmaxf(m8, redm[i]);
    float e0 = __expf(p0 - m8);
    float sm = e0;
    #pragma unroll
    for (int off = 32; off > 0; off >>= 1) sm += __shfl_xor(sm, off, 64);
    if (lane == 0) reds[wid] = sm;
    __syncthreads();
    float ssum = reds[0];
    #pragma unroll
    for (int i = 1; i < 8; ++i) ssum += reds[i];

    float aw0 = actw[0], aw1 = actw[1], aw2 = actw[2];
    scale[b * C_ + tid] = aw0 * fmaxf(p0, 0.f)
                        + aw1 * (1.f / (1.f + __expf(-p0)))
                        + aw2 * (e0 / ssum);
}

// ---------------------------------------------------------------------------
// Fallback-path scale kernel (original, from pooled)
// ---------------------------------------------------------------------------
__global__ __launch_bounds__(512) void k_scale(const float* __restrict__ pooled,
                        const float* __restrict__ ffnn1_w,
                        const float* __restrict__ ffnn1_b,
                        const float* __restrict__ actw,
                        float* __restrict__ scale) {
    int b = blockIdx.x;
    int c = threadIdx.x;
    __shared__ float sp[C_];
    __shared__ float red[8];

    sp[c] = pooled[b * C_ + c];
    __syncthreads();

    float acc = ffnn1_b[c];
    const float* wr = ffnn1_w + (size_t)c * C_;
    #pragma unroll 8
    for (int j = 0; j < C_; ++j) acc = fmaf(wr[j], sp[j], acc);

    int wid = c >> 6, lane = c & 63;
    float m = acc;
    #pragma unroll
    for (int off = 32; off > 0; off >>= 1) m = fmaxf(m, __shfl_down(m, off, 64));
    if (lane == 0) red[wid] = m;
    __syncthreads();
    if (c == 0) {
        float mm = red[0];
        #pragma unroll
        for (int i = 1; i < 8; ++i) mm = fmaxf(mm, red[i]);
        red[0] = mm;
    }
    __syncthreads();
    m = red[0];
    __syncthreads();

    float e = __expf(acc - m);
    float s = e;
    #pragma unroll
    for (int off = 32; off > 0; off >>= 1) s += __shfl_down(s, off, 64);
    if (lane == 0) red[wid] = s;
    __syncthreads();
    if (c == 0) {
        float ss = 0.f;
        #pragma unroll
        for (int i = 0; i < 8; ++i) ss += red[i];
        red[0] = ss;
    }
    __syncthreads();
    s = red[0];

    float w0 = actw[0], w1 = actw[1], w2 = actw[2];
    float val = w0 * fmaxf(acc, 0.f)
              + w1 * (1.f / (1.f + __expf(-acc)))
              + w2 * (e / s);
    scale[b * C_ + c] = val;
}

// ---------------------------------------------------------------------------
// Kernel 4 (MFMA v8, 4-phase interleaved, m201-pattern port):
// one GEMM  M=2560, N=8192 (b*512+c), K=1280
//   C[g,n] = sum_k G3w[g,k] * X[b, k/256, c, k%256],  n = b*512+c
//   out[b, g>>8, c, g&255] = scale[b,c] * (C + g3b[g])
//
// BM=320 x BN=256 x BK=32, 512 threads (8 waves, 2M x 4N), per-wave 160x64,
// acc[10][4]. Grid 256 = EXACTLY 1 block/CU, zero tail. XCD owns
// 4 N-tiles x 8 M-tiles. 3 LDS buffers (108 KB), depth-2 prefetch.
// Per K-step, FOUR fine phases (one C-quadrant each, m201 granularity):
//   {ds_read quadrant frags || 1-2 stage loads -> s_barrier -> lgkmcnt(0)
//    + sched_barrier -> setprio(1) -> 10 MFMA -> setprio(0)}
// Counted vmcnt(5|4) ONCE per step at phase 4 (never 0 mid-loop): t+2's
// per-thread loads (5 if tid<256 else 4) stay in flight; in-order retirement
// guarantees tile t+1 resident. Race-safety: all reads of buf[cur] are
// lgkmcnt-complete before phase-4's barrier; the next step stages into
// buf[cur] only after that barrier; phase-4 MFMAs touch registers only.
// ---------------------------------------------------------------------------
#define BM 320
#define BN 256
#define BK 32
#define NKT (KIN_ / BK)          // 40
#define ABUF (BM * BK)           // 10240 u16 = 20 KB
#define BBUF (BN * BK)           // 8192 u16 = 16 KB
#define BUFU (ABUF + BBUF)       // 18432 u16 = 36 KB

__device__ __forceinline__ void gload16(const void* g, void* l) {
    __builtin_amdgcn_global_load_lds(
        (const __attribute__((address_space(1))) void*)g,
        (__attribute__((address_space(3))) void*)l, 16, 0, 0);
}

__global__ __launch_bounds__(512, 1) void k_gemm_mfma(
    const u16* __restrict__ A,   // bf16 [GOUT_][KIN_]
    const u16* __restrict__ X,   // bf16 [B_][T_][C_][HW_]
    const float* __restrict__ g3b,
    const float* __restrict__ scale,
    float* __restrict__ out)
{
    __shared__ u16 lds[3 * BUFU];            // 108 KiB

    // grid 256 = 8 XCDs x 32: each XCD owns 4 consecutive N-tiles x 8 M-tiles
    int orig = blockIdx.x;
    int xcd  = orig & 7;
    int idx  = orig >> 3;                    // 0..31
    int nt   = xcd * 4 + (idx >> 3);         // 0..31
    int gt   = idx & 7;                      // 0..7
    int g0   = gt * BM;
    int b    = nt >> 1;                      // batch
    int c0   = (nt & 1) * BN;                // col within batch

    int tid = threadIdx.x;
    int lane = tid & 63, wid = tid >> 6;     // 8 waves
    int wr = wid >> 2, wc = wid & 3;         // 2M x 4N
    int lrow = lane & 15, lslot = lane >> 4;

    // staging geometry (rule #21 pair): chunk q -> row r=q>>2, phys slot
    // p=q&3 (LDS linear at q*8 u16); global src slot s = p ^ ((r>>1)&3)
    // A: 1280 chunks: q=tid, q=512+tid, q=1024+tid (tid<256)
    // B: 1024 chunks: q=tid, q=512+tid
    int offA0, offA1, offA2, offB0, offB1;
    {
        int q, r, p;
        q = tid;         r = q >> 2; p = q & 3; offA0 = r * KIN_ + (p ^ ((r >> 1) & 3)) * 8;
        q = 512 + tid;   r = q >> 2; p = q & 3; offA1 = r * KIN_ + (p ^ ((r >> 1) & 3)) * 8;
        q = 1024 + tid;  r = q >> 2; p = q & 3; offA2 = r * KIN_ + (p ^ ((r >> 1) & 3)) * 8;
        q = tid;         r = q >> 2; p = q & 3; offB0 = r * HW_  + (p ^ ((r >> 1) & 3)) * 8;
        q = 512 + tid;   r = q >> 2; p = q & 3; offB1 = r * HW_  + (p ^ ((r >> 1) & 3)) * 8;
    }
    int wb = wid * 512;                      // wave-uniform LDS write base (u16)

    const u16* Abase = A + (size_t)g0 * KIN_;
    #define XOFF(kt) ((((size_t)(b * T_ + ((kt) >> 3)) * C_) + c0) * HW_ + ((kt) & 7) * 32)

    // full-tile stage (prologue only)
    #define STAGE_ALL(D, sA, sX)                                             \
    {                                                                        \
        gload16((sA) + offA0, (D) + wb);                                     \
        gload16((sA) + offA1, (D) + 4096 + wb);                              \
        if (tid < 256) gload16((sA) + offA2, (D) + 8192 + wb);               \
        gload16((sX) + offB0, (D) + ABUF + wb);                              \
        gload16((sX) + offB1, (D) + ABUF + 4096 + wb);                       \
    }

    // ---- prologue: stage tiles 0,1 (depth-2)
    STAGE_ALL(lds,        Abase,      X + XOFF(0));
    STAGE_ALL(lds + BUFU, Abase + BK, X + XOFF(1));
    if (tid < 256) asm volatile("s_waitcnt vmcnt(5)" ::: "memory");
    else           asm volatile("s_waitcnt vmcnt(4)" ::: "memory");
    __builtin_amdgcn_s_barrier();

    f32x4 acc[10][4];
    #pragma unroll
    for (int mI = 0; mI < 10; ++mI)
        #pragma unroll
        for (int n = 0; n < 4; ++n) acc[mI][n] = (f32x4)0.f;

    int cur = 0;
    for (int t = 0; t < NKT; ++t) {
        const u16* Ac = lds + cur * BUFU;
        const u16* Bc = Ac + ABUF;
        bool pre2 = (t + 2) < NKT;
        int nx = cur + 2; if (nx >= 3) nx -= 3;
        u16* Dn = lds + nx * BUFU;
        const u16* sA = Abase + (size_t)(t + 2) * BK;
        const u16* sX = X + XOFF(pre2 ? (t + 2) : 0);

        s16x8 b0, b1, b2, b3, a0[5], a1[5];

        // ======== phase 1: frags b0,b1 + a0[0..4]; stage offA0; 10 MFMA
        {
            int r0 = wc * 64 + lrow,     p0 = lslot ^ ((r0 >> 1) & 3);
            int r1 = wc * 64 + 16 + lrow, p1 = lslot ^ ((r1 >> 1) & 3);
            b0 = *reinterpret_cast<const s16x8*>(Bc + r0 * BK + p0 * 8);
            b1 = *reinterpret_cast<const s16x8*>(Bc + r1 * BK + p1 * 8);
            #pragma unroll
            for (int mI = 0; mI < 5; ++mI) {
                int r = wr * 160 + mI * 16 + lrow;
                int p = lslot ^ ((r >> 1) & 3);
                a0[mI] = *reinterpret_cast<const s16x8*>(Ac + r * BK + p * 8);
            }
        }
        if (pre2) gload16(sA + offA0, Dn + wb);
        __builtin_amdgcn_s_barrier();
        asm volatile("s_waitcnt lgkmcnt(0)" ::: "memory");
        __builtin_amdgcn_sched_barrier(0);
        __builtin_amdgcn_s_setprio(1);
        #pragma unroll
        for (int mI = 0; mI < 5; ++mI) {
            acc[mI][0] = __builtin_amdgcn_mfma_f32_16x16x32_bf16(a0[mI], b0, acc[mI][0], 0, 0, 0);
            acc[mI][1] = __builtin_amdgcn_mfma_f32_16x16x32_bf16(a0[mI], b1, acc[mI][1], 0, 0, 0);
        }
        __builtin_amdgcn_s_setprio(0);

        // ======== phase 2: frags b2,b3; stage offA1; 10 MFMA
        {
            int r2 = wc * 64 + 32 + lrow, p2 = lslot ^ ((r2 >> 1) & 3);
            int r3 = wc * 64 + 48 + lrow, p3 = lslot ^ ((r3 >> 1) & 3);
            b2 = *reinterpret_cast<const s16x8*>(Bc + r2 * BK + p2 * 8);
            b3 = *reinterpret_cast<const s16x8*>(Bc + r3 * BK + p3 * 8);
        }
        if (pre2) gload16(sA + offA1, Dn + 4096 + wb);
        __builtin_amdgcn_s_barrier();
        asm volatile("s_waitcnt lgkmcnt(0)" ::: "memory");
        __builtin_amdgcn_sched_barrier(0);
        __builtin_amdgcn_s_setprio(1);
        #pragma unroll
        for (int mI = 0; mI < 5; ++mI) {
            acc[mI][2] = __builtin_amdgcn_mfma_f32_16x16x32_bf16(a0[mI], b2, acc[mI][2], 0, 0, 0);
            acc[mI][3] = __builtin_amdgcn_mfma_f32_16x16x32_bf16(a0[mI], b3, acc[mI][3], 0, 0, 0);
        }
        __builtin_amdgcn_s_setprio(0);

        // ======== phase 3: frags a1[0..4]; stage offA2 + offB0; 10 MFMA
        #pragma unroll
        for (int mI = 0; mI < 5; ++mI) {
            int r = wr * 160 + (mI + 5) * 16 + lrow;
            int p = lslot ^ ((r >> 1) & 3);
            a1[mI] = *reinterpret_cast<const s16x8*>(Ac + r * BK + p * 8);
        }
        if (pre2) {
            if (tid < 256) gload16(sA + offA2, Dn + 8192 + wb);
            gload16(sX + offB0, Dn + ABUF + wb);
        }
        __builtin_amdgcn_s_barrier();
        asm volatile("s_waitcnt lgkmcnt(0)" ::: "memory");
        __builtin_amdgcn_sched_barrier(0);
        __builtin_amdgcn_s_setprio(1);
        #pragma unroll
        for (int mI = 0; mI < 5; ++mI) {
            acc[mI + 5][0] = __builtin_amdgcn_mfma_f32_16x16x32_bf16(a1[mI], b0, acc[mI + 5][0], 0, 0, 0);
            acc[mI + 5][1] = __builtin_amdgcn_mfma_f32_16x16x32_bf16(a1[mI], b1, acc[mI + 5][1], 0, 0, 0);
        }
        __builtin_amdgcn_s_setprio(0);

        // ======== phase 4: stage offB1; counted vmcnt; barrier; 10 MFMA
        if (pre2) gload16(sX + offB1, Dn + ABUF + 4096 + wb);
        if (pre2) {
            if (tid < 256) asm volatile("s_waitcnt vmcnt(5)" ::: "memory");
            else           asm volatile("s_waitcnt vmcnt(4)" ::: "memory");
        } else {
            asm volatile("s_waitcnt vmcnt(0)" ::: "memory");
        }
        __builtin_amdgcn_s_barrier();
        __builtin_amdgcn_s_setprio(1);
        #pragma unroll
        for (int mI = 0; mI < 5; ++mI) {
            acc[mI + 5][2] = __builtin_amdgcn_mfma_f32_16x16x32_bf16(a1[mI], b2, acc[mI + 5][2], 0, 0, 0);
            acc[mI + 5][3] = __builtin_amdgcn_mfma_f32_16x16x32_bf16(a1[mI], b3, acc[mI + 5][3], 0, 0, 0);
        }
        __builtin_amdgcn_s_setprio(0);

        ++cur; if (cur >= 3) cur -= 3;
    }

    // ---- epilogue: D row -> g, col -> c  (validated m89 layout)
    #pragma unroll
    for (int n = 0; n < 4; ++n) {
        int c = c0 + wc * 64 + n * 16 + lrow;
        float sc = scale[b * C_ + c];
        #pragma unroll
        for (int mI = 0; mI < 10; ++mI) {
            int g  = g0 + wr * 160 + mI * 16 + lslot * 4;   // 4-aligned
            int f  = g >> 8;
            int hw = g & 255;
            float4 bias = *reinterpret_cast<const float4*>(g3b + g);
            f32x4 v = acc[mI][n];
            float4 o;
            o.x = sc * (v[0] + bias.x);
            o.y = sc * (v[1] + bias.y);
            o.z = sc * (v[2] + bias.z);
            o.w = sc * (v[3] + bias.w);
            *reinterpret_cast<float4*>(
                out + (((size_t)(b * NF_ + f) * C_ + c) * HW_ + hw)) = o;
        }
    }
    #undef XOFF
    #undef STAGE_ALL
}

// ---------------------------------------------------------------------------
// Fallback fp32 GEMM (round-1, known-correct) in case ws_size is too small
// ---------------------------------------------------------------------------
#define FBM 128
#define FBN 128
#define FBK 32
__global__ __launch_bounds__(256) void k_gemm_fp32(
    const float* __restrict__ in,
    const float* __restrict__ g3w,
    const float* __restrict__ g3b,
    const float* __restrict__ scale,
    float* __restrict__ out)
{
    int b  = blockIdx.y;
    int gt = blockIdx.x >> 2;
    int ct = blockIdx.x & 3;
    int g0 = gt * FBM, c0 = ct * FBN;
    int tid = threadIdx.x;
    int ty = tid & 15;
    int tx = tid >> 4;

    __shared__ float As[FBK][FBM + 4];
    __shared__ float Bs[FBK][FBN + 4];

    float acc[8][8];
    #pragma unroll
    for (int i = 0; i < 8; ++i)
        #pragma unroll
        for (int j = 0; j < 8; ++j) acc[i][j] = 0.f;

    for (int k0 = 0; k0 < KIN_; k0 += FBK) {
        int t   = k0 >> 8;
        int hw0 = k0 & 255;
        #pragma unroll
        for (int p = 0; p < 16; ++p) {
            int idx = tid + p * 256;
            int kk = idx & 31, gg = idx >> 5;
            As[kk][gg] = g3w[(size_t)(g0 + gg) * KIN_ + k0 + kk];
        }
        const float* bsrc = in + ((size_t)(b * T_ + t) * C_ + c0) * HW_ + hw0;
        #pragma unroll
        for (int p = 0; p < 16; ++p) {
            int idx = tid + p * 256;
            int kk = idx & 31, cc = idx >> 5;
            Bs[kk][cc] = bsrc[(size_t)cc * HW_ + kk];
        }
        __syncthreads();
        #pragma unroll
        for (int kk = 0; kk < FBK; ++kk) {
            float a[8], bb[8];
            #pragma unroll
            for (int i = 0; i < 8; ++i) a[i] = As[kk][ty * 8 + i];
            #pragma unroll
            for (int j = 0; j < 8; ++j) bb[j] = Bs[kk][tx * 8 + j];
            #pragma unroll
            for (int i = 0; i < 8; ++i)
                #pragma unroll
                for (int j = 0; j < 8; ++j)
                    acc[i][j] = fmaf(a[i], bb[j], acc[i][j]);
        }
        __syncthreads();
    }

    int gl = ty * 8;
    int g  = g0 + gl;
    int f  = g >> 8;
    int hw = g & 255;
    #pragma unroll
    for (int j = 0; j < 8; ++j) {
        int c = c0 + tx * 8 + j;
        float sc = scale[b * C_ + c];
        float* op = out + (((size_t)(b * NF_ + f) * C_ + c) * HW_ + hw);
        float4 v0, v1;
        v0.x = sc * (acc[0][j] + g3b[g + 0]);
        v0.y = sc * (acc[1][j] + g3b[g + 1]);
        v0.z = sc * (acc[2][j] + g3b[g + 2]);
        v0.w = sc * (acc[3][j] + g3b[g + 3]);
        v1.x = sc * (acc[4][j] + g3b[g + 4]);
        v1.y = sc * (acc[5][j] + g3b[g + 5]);
        v1.z = sc * (acc[6][j] + g3b[g + 6]);
        v1.w = sc * (acc[7][j] + g3b[g + 7]);
        reinterpret_cast<float4*>(op)[0] = v0;
        reinterpret_cast<float4*>(op)[1] = v1;
    }
}

// ---------------------------------------------------------------------------
extern "C" void kernel_launch(void* const* d_in, const int* in_sizes, int n_in,
                              void* d_out, int out_size, void* d_ws, size_t ws_size,
                              hipStream_t stream) {
    const float* input    = (const float*)d_in[0];
    const float* actw     = (const float*)d_in[2];
    const float* conv1_w  = (const float*)d_in[3];
    const float* conv1_b  = (const float*)d_in[4];
    const float* g3w      = (const float*)d_in[5];
    const float* g3b      = (const float*)d_in[6];
    const float* ffnn1_w  = (const float*)d_in[7];
    const float* ffnn1_b  = (const float*)d_in[8];
    float* out = (float*)d_out;

    float* ws     = (float*)d_ws;
    float* wbar   = ws;                    // 1280
    float* bbar   = ws + KIN_;             // 1
    float* pooled = ws + 1536;             // 8192 (reused as scale after k_pre)
    float* pre    = ws + 1536 + B_ * C_;   // 8192
    float* scale  = pooled;                // pooled dead after k_pre -> reuse
    u16* wsA = (u16*)(ws + 17920);                       // 2560*1280 bf16
    u16* wsX = wsA + (size_t)GOUT_ * KIN_;               // 16*5*512*256 bf16
    const size_t need = 71680ull + (size_t)GOUT_ * KIN_ * 2 + (size_t)B_ * T_ * C_ * HW_ * 2;

    if (ws_size >= need) {
        k_init<<<dim3(5 + CASTW_BLKS), dim3(256), 0, stream>>>(
            conv1_w, conv1_b, wbar, bbar, g3w, wsA);
        k_prep<<<dim3(FUSE_BLKS), dim3(256), 0, stream>>>(
            input, wbar, bbar, pooled, wsX);
        k_pre<<<dim3(256), dim3(256), 0, stream>>>(pooled, ffnn1_w, ffnn1_b, pre);
        k_act<<<dim3(B_), dim3(512), 0, stream>>>(pre, actw, scale);
        k_gemm_mfma<<<dim3(256), dim3(512), 0, stream>>>(
            wsA, wsX, g3b, scale, out);
    } else {
        k_wbar<<<dim3((KIN_ + 255) / 256), dim3(256), 0, stream>>>(conv1_w, conv1_b, wbar, bbar);
        k_pooled<<<dim3(B_ * C_), dim3(256), 0, stream>>>(input, wbar, bbar, pooled);
        k_scale<<<dim3(B_), dim3(512), 0, stream>>>(pooled, ffnn1_w, ffnn1_b, actw, pre);
        k_gemm_fp32<<<dim3((GOUT_ / FBM) * (C_ / FBN), B_), dim3(256), 0, stream>>>(
            input, g3w, g3b, pre, out);
    }
}